// Round 3
// baseline (790.030 us; speedup 1.0000x reference)
//
#include <hip/hip_runtime.h>

typedef unsigned short u16;
typedef unsigned int   u32;
typedef u16   u16x4  __attribute__((ext_vector_type(4)));
typedef u16   u16x8  __attribute__((ext_vector_type(8)));
typedef short bf16x8 __attribute__((ext_vector_type(8)));
typedef float f32x4  __attribute__((ext_vector_type(4)));

#define B_    2
#define L_    2048
#define DM_   1024
#define H_    16
#define NEG_BIG   (-9.2233720368547758e18f)
#define INV_SQRT_L 0.022097086912079608f   /* 1/sqrt(2048) */

#define MFMA16(a, b, c) __builtin_amdgcn_mfma_f32_16x16x32_bf16((a), (b), (c), 0, 0, 0)

__device__ __forceinline__ u16 f2bf(float f) {            // RNE fp32->bf16
  u32 u = __builtin_bit_cast(u32, f);
  u32 r = (u + 0x7fffu + ((u >> 16) & 1u)) >> 16;
  return (u16)r;
}
__device__ __forceinline__ float bf2f(u16 h) {
  return __builtin_bit_cast(float, (u32)((u32)h << 16));
}

// Stage a 128x64 bf16 tile (16KB) global->LDS, linear LDS dest,
// XOR-swizzled SOURCE so reads with the same XOR are bank-conflict-free (T2 / rule 21c).
__device__ __forceinline__ void stage_tile16(const u16* g, u16* lds, long rowStrideBytes, int tid) {
  const int lane = tid & 63, wv = tid >> 6;
#pragma unroll
  for (int i = 0; i < 4; ++i) {
    const int obase = wv * 4096 + i * 1024;          // wave-uniform LDS byte base
    const int o = obase + lane * 16;                 // this lane's 16B slot
    const int row = o >> 7;                          // 128B per row
    const int col = (o & 127) ^ ((row & 7) << 4);    // inverse-swizzled source col
    const char* src = (const char*)g + (long)row * rowStrideBytes + col;
    __builtin_amdgcn_global_load_lds(
        (const __attribute__((address_space(1))) void*)src,
        (__attribute__((address_space(3))) void*)((char*)lds + obase),
        16, 0, 0);
  }
}

// Read an 8-bf16 MFMA fragment slice from a swizzled 128x64 tile.
__device__ __forceinline__ bf16x8 read_frag(const u16* lds, int row, int colByte) {
  const int c = colByte ^ ((row & 7) << 4);
  return *(const bf16x8*)((const char*)lds + row * 128 + c);
}

// ---------------------------------------------------------------------------
// Convert inputs to bf16 scratch, pack QKV biases, precompute additive mask.
// ---------------------------------------------------------------------------
__global__ __launch_bounds__(256)
void convert_kernel(const float* __restrict__ q, const float* __restrict__ k,
                    const float* __restrict__ v,
                    const float* __restrict__ wq, const float* __restrict__ wk,
                    const float* __restrict__ wv, const float* __restrict__ wo,
                    const float* __restrict__ bq, const float* __restrict__ bk,
                    const float* __restrict__ bv, const int* __restrict__ mask,
                    u16* __restrict__ dst, float* __restrict__ biasQKV,
                    float* __restrict__ amBuf)
{
  const long stride = (long)gridDim.x * blockDim.x;
  const long t0 = (long)blockIdx.x * blockDim.x + threadIdx.x;
  for (long c = t0; c < (1l << 22); c += stride) {   // 16M elems / 4 per chunk
    const long e = c << 2;
    const float* src; long off;
    if (e < (1l << 22))      { src = q; off = e; }
    else if (e < (2l << 22)) { src = k; off = e - (1l << 22); }
    else if (e < (3l << 22)) { src = v; off = e - (2l << 22); }
    else {
      const long w = e - (3l << 22);
      const int seg = (int)(w >> 20);
      off = w & ((1l << 20) - 1);
      src = (seg == 0) ? wq : (seg == 1) ? wk : (seg == 2) ? wv : wo;
    }
    const float4 f = *(const float4*)(src + off);
    u16x4 o4; o4[0] = f2bf(f.x); o4[1] = f2bf(f.y); o4[2] = f2bf(f.z); o4[3] = f2bf(f.w);
    *(u16x4*)(dst + e) = o4;
  }
  if (t0 < 3072)
    biasQKV[t0] = (t0 < 1024) ? bq[t0] : (t0 < 2048) ? bk[t0 - 1024] : bv[t0 - 2048];
  if (t0 < (long)B_ * L_) {
    float am = 1.0f - (float)mask[t0];
    if (am == 1.0f) am = NEG_BIG;    // quirky reference mask semantics
    amBuf[t0] = am;
  }
}

// ---------------------------------------------------------------------------
// Batched NT GEMM: C[M,N] = A[M,K] * Bw[N,K]^T + bias.  128x128 tile, BK=64,
// 4 waves x (64x64), mfma_f32_16x16x32_bf16. z = batch index.
// ---------------------------------------------------------------------------
template <bool F32OUT>
__global__ __launch_bounds__(256)
void gemm_nt(const u16* __restrict__ A, const u16* __restrict__ Bw,
             const float* __restrict__ bias, void* __restrict__ Cv,
             int M, int N, int K,
             long aBatch, long bBatch, long biasBatch, long cBatch)
{
  __shared__ u16 sA[8192];
  __shared__ u16 sB[8192];
  const int z = blockIdx.z;
  A += (long)z * aBatch; Bw += (long)z * bBatch; bias += (long)z * biasBatch;
  const int tid = threadIdx.x, lane = tid & 63;
  const int wr = tid >> 7, wc = (tid >> 6) & 1;
  const int brow = blockIdx.y * 128, bcol = blockIdx.x * 128;

  f32x4 acc[4][4];
#pragma unroll
  for (int m = 0; m < 4; ++m)
#pragma unroll
    for (int n = 0; n < 4; ++n) acc[m][n] = (f32x4){0.f, 0.f, 0.f, 0.f};

  for (int kt = 0; kt < K; kt += 64) {
    stage_tile16(A + (long)brow * K + kt, sA, (long)K * 2, tid);
    stage_tile16(Bw + (long)bcol * K + kt, sB, (long)K * 2, tid);
    __syncthreads();
#pragma unroll
    for (int kk = 0; kk < 2; ++kk) {
      bf16x8 af[4], bfr[4];
#pragma unroll
      for (int m = 0; m < 4; ++m)
        af[m] = read_frag(sA, wr * 64 + m * 16 + (lane & 15), kk * 64 + (lane >> 4) * 16);
#pragma unroll
      for (int n = 0; n < 4; ++n)
        bfr[n] = read_frag(sB, wc * 64 + n * 16 + (lane & 15), kk * 64 + (lane >> 4) * 16);
#pragma unroll
      for (int m = 0; m < 4; ++m)
#pragma unroll
        for (int n = 0; n < 4; ++n)
          acc[m][n] = MFMA16(af[m], bfr[n], acc[m][n]);
    }
    __syncthreads();
  }

#pragma unroll
  for (int n = 0; n < 4; ++n) {
    const int col = bcol + wc * 64 + n * 16 + (lane & 15);
    const float bv = bias[col];
#pragma unroll
    for (int m = 0; m < 4; ++m) {
      const int row0 = brow + wr * 64 + m * 16 + ((lane >> 4) << 2);
#pragma unroll
      for (int r = 0; r < 4; ++r) {
        const float val = acc[m][n][r] + bv;
        const long idx = (long)z * cBatch + (long)(row0 + r) * N + col;
        if (F32OUT) ((float*)Cv)[idx] = val;
        else        ((u16*)Cv)[idx]   = f2bf(val);
      }
    }
  }
}

// ---------------------------------------------------------------------------
// Pass 1 of attention: per-row sum of exp((QK^T + am)/sqrt(L)) -> reciprocal.
// Grid: (L/128, B*H). 4 waves, each 64x64 of the 128x128 score tile.
// ---------------------------------------------------------------------------
__global__ __launch_bounds__(256, 2)
void attn_rowsum(const u16* __restrict__ Qp, const u16* __restrict__ Kp,
                 const float* __restrict__ amBuf, float* __restrict__ rowRecip)
{
  __shared__ u16 sT[8192];      // 16KB: Q staging first, then K tiles
  __shared__ float sSum[128];
  const int tid = threadIdx.x, lane = tid & 63;
  const int wr = tid >> 7, wc = (tid >> 6) & 1;
  const int bh = blockIdx.y, b = bh >> 4, h = bh & 15;
  const int q0 = blockIdx.x * 128;

  stage_tile16(Qp + ((long)(b * L_ + q0)) * DM_ + h * 64, sT, DM_ * 2, tid);
  __syncthreads();
  bf16x8 qf[4][2];
#pragma unroll
  for (int m = 0; m < 4; ++m)
#pragma unroll
    for (int kk = 0; kk < 2; ++kk)
      qf[m][kk] = read_frag(sT, wr * 64 + m * 16 + (lane & 15), kk * 64 + (lane >> 4) * 16);
  __syncthreads();

  float rs[4][4];
#pragma unroll
  for (int m = 0; m < 4; ++m)
#pragma unroll
    for (int r = 0; r < 4; ++r) rs[m][r] = 0.f;

  const float* amB = amBuf + b * L_;
  for (int kt = 0; kt < 16; ++kt) {
    stage_tile16(Kp + ((long)(b * L_ + kt * 128)) * DM_ + h * 64, sT, DM_ * 2, tid);
    __syncthreads();
    f32x4 acc[4][4];
#pragma unroll
    for (int m = 0; m < 4; ++m)
#pragma unroll
      for (int n = 0; n < 4; ++n) acc[m][n] = (f32x4){0.f, 0.f, 0.f, 0.f};
#pragma unroll
    for (int kk = 0; kk < 2; ++kk) {
      bf16x8 kf[4];
#pragma unroll
      for (int n = 0; n < 4; ++n)
        kf[n] = read_frag(sT, wc * 64 + n * 16 + (lane & 15), kk * 64 + (lane >> 4) * 16);
#pragma unroll
      for (int m = 0; m < 4; ++m)
#pragma unroll
        for (int n = 0; n < 4; ++n)
          acc[m][n] = MFMA16(qf[m][kk], kf[n], acc[m][n]);
    }
#pragma unroll
    for (int n = 0; n < 4; ++n) {
      const float am = amB[kt * 128 + wc * 64 + n * 16 + (lane & 15)];
#pragma unroll
      for (int m = 0; m < 4; ++m)
#pragma unroll
        for (int r = 0; r < 4; ++r)
          rs[m][r] += __expf((acc[m][n][r] + am) * INV_SQRT_L);
    }
    __syncthreads();
  }

  // reduce over 16 lanes sharing a row, then combine the two col-half waves
  float vr[4][4];
#pragma unroll
  for (int m = 0; m < 4; ++m)
#pragma unroll
    for (int r = 0; r < 4; ++r) {
      float s = rs[m][r];
      s += __shfl_xor(s, 1); s += __shfl_xor(s, 2);
      s += __shfl_xor(s, 4); s += __shfl_xor(s, 8);
      vr[m][r] = s;
      const int row = wr * 64 + m * 16 + ((lane >> 4) << 2) + r;
      if (wc == 1 && (lane & 15) == 0) sSum[row] = s;
    }
  __syncthreads();
#pragma unroll
  for (int m = 0; m < 4; ++m)
#pragma unroll
    for (int r = 0; r < 4; ++r) {
      const int row = wr * 64 + m * 16 + ((lane >> 4) << 2) + r;
      if (wc == 0 && (lane & 15) == 0)
        rowRecip[((long)bh << 11) + q0 + row] = 1.0f / (vr[m][r] + sSum[row]);
    }
}

// ---------------------------------------------------------------------------
// Pass 2: recompute QK^T, normalize, write fp32 scores (coalesced via LDS),
// and accumulate PV with MFMA. K-tile staging aliases the P LDS tile
// (live ranges disjoint) to keep LDS at 52KB -> 2 blocks/CU.
// ---------------------------------------------------------------------------
__global__ __launch_bounds__(256, 2)
void attn_scores_pv(const u16* __restrict__ Qp, const u16* __restrict__ Kp,
                    const u16* __restrict__ Vp, const float* __restrict__ amBuf,
                    const float* __restrict__ rowRecip,
                    float* __restrict__ scoresOut, u16* __restrict__ blendedOut)
{
  __shared__ u16 sPt[128 * 136];   // padded P tile; first 16KB doubles as K/Q staging
  __shared__ u16 sVt[64 * 136];    // padded V^T tile
  u16* sK = sPt;

  const int tid = threadIdx.x, lane = tid & 63, wvid = tid >> 6;
  const int wr = tid >> 7, wc = (tid >> 6) & 1;
  const int bh = blockIdx.y, b = bh >> 4, h = bh & 15;
  const int q0 = blockIdx.x * 128;

  stage_tile16(Qp + ((long)(b * L_ + q0)) * DM_ + h * 64, sPt, DM_ * 2, tid);
  __syncthreads();
  bf16x8 qf[4][2];
#pragma unroll
  for (int m = 0; m < 4; ++m)
#pragma unroll
    for (int kk = 0; kk < 2; ++kk)
      qf[m][kk] = read_frag(sPt, wr * 64 + m * 16 + (lane & 15), kk * 64 + (lane >> 4) * 16);
  float inv[4][4];
#pragma unroll
  for (int m = 0; m < 4; ++m)
#pragma unroll
    for (int r = 0; r < 4; ++r)
      inv[m][r] = rowRecip[((long)bh << 11) + q0 + wr * 64 + m * 16 + ((lane >> 4) << 2) + r];

  f32x4 pv[2][4];
#pragma unroll
  for (int m2 = 0; m2 < 2; ++m2)
#pragma unroll
    for (int n2 = 0; n2 < 4; ++n2) pv[m2][n2] = (f32x4){0.f, 0.f, 0.f, 0.f};

  const float* amB = amBuf + b * L_;
  const long scoreBase = (((long)bh << 11) + q0) << 11;   // (bh*L + q0) * L

  for (int kt = 0; kt < 16; ++kt) {
    __syncthreads();   // (A) prior readers of sPt/sVt done
    stage_tile16(Kp + ((long)(b * L_ + kt * 128)) * DM_ + h * 64, sK, DM_ * 2, tid);
    // stage V tile transposed: sVt[d][kkr]
#pragma unroll
    for (int i = 0; i < 8; ++i) {
      const int idx = i * 256 + tid;          // 2048 u16x4 chunks
      const int kkr = idx >> 4;
      const int d4 = (idx & 15) << 2;
      const u16x4 vv = *(const u16x4*)(Vp + ((long)(b * L_ + kt * 128 + kkr)) * DM_ + h * 64 + d4);
      sVt[(d4 + 0) * 136 + kkr] = vv[0];
      sVt[(d4 + 1) * 136 + kkr] = vv[1];
      sVt[(d4 + 2) * 136 + kkr] = vv[2];
      sVt[(d4 + 3) * 136 + kkr] = vv[3];
    }
    __syncthreads();   // (B) K + V^T visible

    f32x4 acc[4][4];
#pragma unroll
    for (int m = 0; m < 4; ++m)
#pragma unroll
      for (int n = 0; n < 4; ++n) acc[m][n] = (f32x4){0.f, 0.f, 0.f, 0.f};
#pragma unroll
    for (int kk = 0; kk < 2; ++kk) {
      bf16x8 kf[4];
#pragma unroll
      for (int n = 0; n < 4; ++n)
        kf[n] = read_frag(sK, wc * 64 + n * 16 + (lane & 15), kk * 64 + (lane >> 4) * 16);
#pragma unroll
      for (int m = 0; m < 4; ++m)
#pragma unroll
        for (int n = 0; n < 4; ++n)
          acc[m][n] = MFMA16(qf[m][kk], kf[n], acc[m][n]);
    }
    __syncthreads();   // (C) QK reads of sK(=sPt) done before P overwrites it

    // normalized P -> padded LDS tile (bf16)
#pragma unroll
    for (int m = 0; m < 4; ++m) {
      const int rowL = wr * 64 + m * 16 + ((lane >> 4) << 2);
#pragma unroll
      for (int n = 0; n < 4; ++n) {
        const int colL = wc * 64 + n * 16 + (lane & 15);
        const float am = amB[kt * 128 + colL];
#pragma unroll
        for (int r = 0; r < 4; ++r) {
          const float p = __expf((acc[m][n][r] + am) * INV_SQRT_L) * inv[m][r];
          sPt[(rowL + r) * 136 + colL] = f2bf(p);
        }
      }
    }
    __syncthreads();   // (D) P tile complete

    // coalesced fp32 scores write-out
#pragma unroll
    for (int j = 0; j < 8; ++j) {
      const int row = j * 16 + (tid >> 4);
      const int c0 = (tid & 15) * 8;
      const u16x8 pr = *(const u16x8*)&sPt[row * 136 + c0];
      f32x4 lo, hi;
      lo[0] = bf2f(pr[0]); lo[1] = bf2f(pr[1]); lo[2] = bf2f(pr[2]); lo[3] = bf2f(pr[3]);
      hi[0] = bf2f(pr[4]); hi[1] = bf2f(pr[5]); hi[2] = bf2f(pr[6]); hi[3] = bf2f(pr[7]);
      float* dst = scoresOut + scoreBase + (long)row * L_ + kt * 128 + c0;
      *(f32x4*)dst = lo;
      *(f32x4*)(dst + 4) = hi;
    }

    // PV: each wave owns 32 q-rows x 64 d, inner dim = this tile's 128 cols
#pragma unroll
    for (int kk2 = 0; kk2 < 4; ++kk2) {
      bf16x8 pa[2], vb[4];
#pragma unroll
      for (int m2 = 0; m2 < 2; ++m2)
        pa[m2] = *(const bf16x8*)&sPt[(wvid * 32 + m2 * 16 + (lane & 15)) * 136 + kk2 * 32 + (lane >> 4) * 8];
#pragma unroll
      for (int n2 = 0; n2 < 4; ++n2)
        vb[n2] = *(const bf16x8*)&sVt[(n2 * 16 + (lane & 15)) * 136 + kk2 * 32 + (lane >> 4) * 8];
#pragma unroll
      for (int m2 = 0; m2 < 2; ++m2)
#pragma unroll
        for (int n2 = 0; n2 < 4; ++n2)
          pv[m2][n2] = MFMA16(pa[m2], vb[n2], pv[m2][n2]);
    }
  }

  // blended (already normalized) -> bf16 scratch, layout [B*L, H*dk]
#pragma unroll
  for (int m2 = 0; m2 < 2; ++m2)
#pragma unroll
    for (int n2 = 0; n2 < 4; ++n2)
#pragma unroll
      for (int r = 0; r < 4; ++r) {
        const int qrow = wvid * 32 + m2 * 16 + ((lane >> 4) << 2) + r;
        const int d = n2 * 16 + (lane & 15);
        blendedOut[((long)(b * L_ + q0 + qrow)) * DM_ + h * 64 + d] = f2bf(pv[m2][n2][r]);
      }
}

// ---------------------------------------------------------------------------
extern "C" void kernel_launch(void* const* d_in, const int* in_sizes, int n_in,
                              void* d_out, int out_size, void* d_ws, size_t ws_size,
                              hipStream_t stream)
{
  (void)in_sizes; (void)n_in; (void)out_size; (void)ws_size;
  const float* q    = (const float*)d_in[0];
  const float* k    = (const float*)d_in[1];
  const float* v    = (const float*)d_in[2];
  const int*   mask = (const int*)d_in[3];
  const float* wq_w = (const float*)d_in[4];
  const float* wq_b = (const float*)d_in[5];
  const float* wk_w = (const float*)d_in[6];
  const float* wk_b = (const float*)d_in[7];
  const float* wv_w = (const float*)d_in[8];
  const float* wv_b = (const float*)d_in[9];
  const float* wo_w = (const float*)d_in[10];
  const float* wo_b = (const float*)d_in[11];

  const size_t M4 = (size_t)1 << 22;   // 4M elems
  const size_t M1 = (size_t)1 << 20;   // 1M elems
  u16* Xq = (u16*)d_ws;                // contiguous bf16 region (layout used by convert)
  u16* Wq = Xq + 3 * M4;
  u16* Qp = Wq + 4 * M1;               // projected Q,K,V (contiguous)
  u16* Bl = Qp + 3 * M4;               // blended bf16
  float* fbase    = (float*)(Bl + M4);
  float* biasQKV  = fbase;             // 3072
  float* amBuf    = fbase + 3072;      // 4096
  float* rowRecip = amBuf + 4096;      // 65536

  float* outMain   = (float*)d_out;
  float* scoresOut = outMain + ((size_t)B_ * L_ * DM_);

  convert_kernel<<<2048, 256, 0, stream>>>(q, k, v, wq_w, wk_w, wv_w, wo_w,
                                           wq_b, wk_b, wv_b, mask,
                                           Xq, biasQKV, amBuf);

  // Q/K/V projections: batched over z (A, weights, bias, C all contiguous)
  gemm_nt<false><<<dim3(8, 32, 3), 256, 0, stream>>>(
      Xq, Wq, biasQKV, (void*)Qp, 4096, 1024, 1024,
      (long)M4, (long)M1, 1024l, (long)M4);

  attn_rowsum<<<dim3(16, 32), 256, 0, stream>>>(Qp, Qp + M4, amBuf, rowRecip);

  attn_scores_pv<<<dim3(16, 32), 256, 0, stream>>>(Qp, Qp + M4, Qp + 2 * M4,
                                                   amBuf, rowRecip, scoresOut, Bl);

  gemm_nt<true><<<dim3(8, 32, 1), 256, 0, stream>>>(
      Bl, Wq + 3 * M1 /*Wo*/, wo_b, (void*)outMain, 4096, 1024, 1024,
      0l, 0l, 0l, 0l);
}